// Round 10
// baseline (634.532 us; speedup 1.0000x reference)
//
#include <hip/hip_runtime.h>
#include <math.h>

// SparseFocalModulation — round 10 (= round 7 resubmit; GPU unavailable 3x):
// dense ops as register-tiled GEMM. Block = 64 rows; 16x16 threads; thread
// owns a 4x4 output tile. LDS: input transposed (stride 68), weights linear.

#define PL 1024   // plist capacity (pairs) per sparse block; expected ~18

__device__ __forceinline__ float gelu_exact(float x) {
    return 0.5f * x * (1.0f + erff(x * 0.70710678118654752440f));
}

// ---------------- K1: xf = feat @ f_W + f_b ; split into q / ctx / gates ----
__global__ __launch_bounds__(256) void k_fused_in(
    const float* __restrict__ feat, const float* __restrict__ fW,
    const float* __restrict__ fb, float* __restrict__ q,
    float* __restrict__ ctx, float* __restrict__ gates, int N)
{
    __shared__ float sA[64 * 68];     // feat_T[k][r]
    __shared__ float sWq[64 * 64];    // fW[k][c], c 0..63
    __shared__ float sWc[64 * 64];    // fW[k][64+c]
    __shared__ float sG[64 * 4];      // fW[k][128+j]
    const int t = threadIdx.x, tx = t & 15, ty = t >> 4;
    const int r0 = blockIdx.x * 64;

    for (int e = t; e < 2112; e += 256) {          // 64 rows x 33 float4
        float4 v = ((const float4*)fW)[e];
        int k = e / 33, c4 = (e - k * 33) * 4;
        if (c4 < 64)       *(float4*)&sWq[k * 64 + c4] = v;
        else if (c4 < 128) *(float4*)&sWc[k * 64 + c4 - 64] = v;
        else               *(float4*)&sG[k * 4] = v;
    }
    #pragma unroll
    for (int rr = 0; rr < 4; ++rr) {
        int r = ty + rr * 16;
        int gr = r0 + r; if (gr >= N) gr = N - 1;
        float4 v = *(const float4*)&feat[(size_t)gr * 64 + tx * 4];
        sA[(tx * 4 + 0) * 68 + r] = v.x;
        sA[(tx * 4 + 1) * 68 + r] = v.y;
        sA[(tx * 4 + 2) * 68 + r] = v.z;
        sA[(tx * 4 + 3) * 68 + r] = v.w;
    }
    __syncthreads();

    const float4 bq = *(const float4*)&fb[tx * 4];
    const float4 bc = *(const float4*)&fb[64 + tx * 4];
    float accq[4][4], accc[4][4];
    #pragma unroll
    for (int m = 0; m < 4; ++m) {
        accq[m][0] = bq.x; accq[m][1] = bq.y; accq[m][2] = bq.z; accq[m][3] = bq.w;
        accc[m][0] = bc.x; accc[m][1] = bc.y; accc[m][2] = bc.z; accc[m][3] = bc.w;
    }
    #pragma unroll
    for (int k = 0; k < 64; ++k) {
        const float4 a  = *(const float4*)&sA[k * 68 + ty * 4];
        const float4 wq = *(const float4*)&sWq[k * 64 + tx * 4];
        const float4 wc = *(const float4*)&sWc[k * 64 + tx * 4];
        const float av[4] = {a.x, a.y, a.z, a.w};
        #pragma unroll
        for (int m = 0; m < 4; ++m) {
            accq[m][0] = fmaf(av[m], wq.x, accq[m][0]);
            accq[m][1] = fmaf(av[m], wq.y, accq[m][1]);
            accq[m][2] = fmaf(av[m], wq.z, accq[m][2]);
            accq[m][3] = fmaf(av[m], wq.w, accq[m][3]);
            accc[m][0] = fmaf(av[m], wc.x, accc[m][0]);
            accc[m][1] = fmaf(av[m], wc.y, accc[m][1]);
            accc[m][2] = fmaf(av[m], wc.z, accc[m][2]);
            accc[m][3] = fmaf(av[m], wc.w, accc[m][3]);
        }
    }
    // gates: col j = tx&3, k-range split over tx>>2 (16 k each), reduce over groups
    float accg[4] = {0.f, 0.f, 0.f, 0.f};
    const int j = tx & 3, ks0 = (tx >> 2) * 16;
    #pragma unroll
    for (int kk = 0; kk < 16; ++kk) {
        const int k = ks0 + kk;
        const float4 a = *(const float4*)&sA[k * 68 + ty * 4];
        const float gw = sG[k * 4 + j];
        accg[0] = fmaf(a.x, gw, accg[0]);
        accg[1] = fmaf(a.y, gw, accg[1]);
        accg[2] = fmaf(a.z, gw, accg[2]);
        accg[3] = fmaf(a.w, gw, accg[3]);
    }
    #pragma unroll
    for (int m = 0; m < 4; ++m) {
        accg[m] += __shfl_xor(accg[m], 4);
        accg[m] += __shfl_xor(accg[m], 8);
    }
    const float bg = fb[128 + j];

    #pragma unroll
    for (int m = 0; m < 4; ++m) {
        const int gr = r0 + ty * 4 + m;
        if (gr < N) {
            float4 oq = {accq[m][0], accq[m][1], accq[m][2], accq[m][3]};
            float4 oc = {accc[m][0], accc[m][1], accc[m][2], accc[m][3]};
            *(float4*)&q[(size_t)gr * 64 + tx * 4]   = oq;
            *(float4*)&ctx[(size_t)gr * 64 + tx * 4] = oc;
            if (tx < 4) gates[(size_t)gr * 4 + j] = accg[m] + bg;
        }
    }
}

// ---------------- K2: sparse non-center offsets -> atomicAdd into sbuf ------
__global__ __launch_bounds__(256) void k_sparse(
    const float* __restrict__ ctx, const int* __restrict__ idx,
    const float* __restrict__ W, float* __restrict__ sbuf,
    int N, int center, int nchunk, int seg)
{
    const int o = blockIdx.x / nchunk;
    if (o == center) return;
    const int chunk = blockIdx.x % nchunk;

    __shared__ int plist[2 * PL];
    __shared__ int pcnt;
    __shared__ float sW[4096];
    if (threadIdx.x == 0) pcnt = 0;
    __syncthreads();

    const int start = chunk * seg;
    const int end   = min(N, start + seg);
    const int* row  = idx + (size_t)o * N;
    if (((N | start) & 3) == 0) {
        const int4* row4 = reinterpret_cast<const int4*>(row + start);
        const int n4 = (end - start) >> 2;
        for (int t = threadIdx.x; t < n4; t += 256) {
            int4 v = row4[t];
            int base = start + t * 4;
            if (v.x >= 0) { int p = atomicAdd(&pcnt, 1); if (p < PL) { plist[2*p] = base;     plist[2*p+1] = v.x; } }
            if (v.y >= 0) { int p = atomicAdd(&pcnt, 1); if (p < PL) { plist[2*p] = base + 1; plist[2*p+1] = v.y; } }
            if (v.z >= 0) { int p = atomicAdd(&pcnt, 1); if (p < PL) { plist[2*p] = base + 2; plist[2*p+1] = v.z; } }
            if (v.w >= 0) { int p = atomicAdd(&pcnt, 1); if (p < PL) { plist[2*p] = base + 3; plist[2*p+1] = v.w; } }
        }
    } else {
        for (int t = start + threadIdx.x; t < end; t += 256) {
            int j = row[t];
            if (j >= 0) { int p = atomicAdd(&pcnt, 1); if (p < PL) { plist[2*p] = t; plist[2*p+1] = j; } }
        }
    }
    __syncthreads();

    const int cnt = min(pcnt, PL);
    if (cnt == 0) return;
    for (int t = threadIdx.x; t < 4096; t += 256) sW[t] = W[(size_t)o * 4096 + t];
    __syncthreads();

    const int lane = threadIdx.x & 63;
    const int lwid = threadIdx.x >> 6;
    for (int p = lwid; p < cnt; p += 4) {
        int i = plist[2 * p];
        int j = plist[2 * p + 1];
        float cv  = ctx[(size_t)j * 64 + lane];
        float acc = 0.0f;
        #pragma unroll
        for (int c = 0; c < 64; ++c)
            acc = fmaf(__shfl(cv, c), sW[c * 64 + lane], acc);
        atomicAdd(&sbuf[(size_t)i * 64 + lane], acc);
    }
}

// ------- K3: y = center-matvec + sbuf + b; ln = LN(gelu(y)); opt. pooling ---
__global__ __launch_bounds__(256) void k_post(
    const float* __restrict__ cin, float* __restrict__ sbuf,
    const float* __restrict__ W, const float* __restrict__ b,
    const float* __restrict__ g, const float* __restrict__ be,
    const int* __restrict__ bid, float* __restrict__ lnout,
    float* __restrict__ psum, float* __restrict__ pcnts,
    int N, int center, int zero_sbuf, int do_pool)
{
    __shared__ float sA[64 * 68];
    __shared__ float sW[64 * 64];
    __shared__ float pool[256];
    const int t = threadIdx.x, tx = t & 15, ty = t >> 4;
    const int r0 = blockIdx.x * 64;

    const float* Wc = W + (size_t)center * 4096;
    for (int e = t; e < 1024; e += 256)
        ((float4*)sW)[e] = ((const float4*)Wc)[e];
    if (do_pool) pool[t] = 0.f;
    #pragma unroll
    for (int rr = 0; rr < 4; ++rr) {
        int r = ty + rr * 16;
        int gr = r0 + r; if (gr >= N) gr = N - 1;
        float4 v = *(const float4*)&cin[(size_t)gr * 64 + tx * 4];
        sA[(tx * 4 + 0) * 68 + r] = v.x;
        sA[(tx * 4 + 1) * 68 + r] = v.y;
        sA[(tx * 4 + 2) * 68 + r] = v.z;
        sA[(tx * 4 + 3) * 68 + r] = v.w;
    }
    __syncthreads();

    const float4 bb4 = *(const float4*)&b[tx * 4];
    float acc[4][4];
    #pragma unroll
    for (int m = 0; m < 4; ++m) {
        const int gr = r0 + ty * 4 + m;
        if (gr < N) {
            float4 s4 = *(const float4*)&sbuf[(size_t)gr * 64 + tx * 4];
            acc[m][0] = bb4.x + s4.x; acc[m][1] = bb4.y + s4.y;
            acc[m][2] = bb4.z + s4.z; acc[m][3] = bb4.w + s4.w;
            if (zero_sbuf) {
                float4 z = {0.f, 0.f, 0.f, 0.f};
                *(float4*)&sbuf[(size_t)gr * 64 + tx * 4] = z;
            }
        } else {
            acc[m][0] = acc[m][1] = acc[m][2] = acc[m][3] = 0.f;
        }
    }
    #pragma unroll
    for (int k = 0; k < 64; ++k) {
        const float4 a = *(const float4*)&sA[k * 68 + ty * 4];
        const float4 w = *(const float4*)&sW[k * 64 + tx * 4];
        const float av[4] = {a.x, a.y, a.z, a.w};
        #pragma unroll
        for (int m = 0; m < 4; ++m) {
            acc[m][0] = fmaf(av[m], w.x, acc[m][0]);
            acc[m][1] = fmaf(av[m], w.y, acc[m][1]);
            acc[m][2] = fmaf(av[m], w.z, acc[m][2]);
            acc[m][3] = fmaf(av[m], w.w, acc[m][3]);
        }
    }

    const float4 g4  = *(const float4*)&g[tx * 4];
    const float4 be4 = *(const float4*)&be[tx * 4];
    #pragma unroll
    for (int m = 0; m < 4; ++m) {
        const int gr = r0 + ty * 4 + m;
        float v0 = gelu_exact(acc[m][0]);
        float v1 = gelu_exact(acc[m][1]);
        float v2 = gelu_exact(acc[m][2]);
        float v3 = gelu_exact(acc[m][3]);
        float s = v0 + v1 + v2 + v3;
        s += __shfl_xor(s, 1); s += __shfl_xor(s, 2);
        s += __shfl_xor(s, 4); s += __shfl_xor(s, 8);
        const float mean = s * 0.015625f;
        const float d0 = v0 - mean, d1 = v1 - mean, d2 = v2 - mean, d3 = v3 - mean;
        float vs = d0*d0 + d1*d1 + d2*d2 + d3*d3;
        vs += __shfl_xor(vs, 1); vs += __shfl_xor(vs, 2);
        vs += __shfl_xor(vs, 4); vs += __shfl_xor(vs, 8);
        const float rstd = rsqrtf(vs * 0.015625f + 1e-5f);
        const float l0 = d0 * rstd * g4.x + be4.x;
        const float l1 = d1 * rstd * g4.y + be4.y;
        const float l2 = d2 * rstd * g4.z + be4.z;
        const float l3 = d3 * rstd * g4.w + be4.w;
        if (gr < N) {
            float4 o = {l0, l1, l2, l3};
            *(float4*)&lnout[(size_t)gr * 64 + tx * 4] = o;
            if (do_pool) {
                const int bbid = bid[gr];
                atomicAdd(&pool[bbid * 64 + tx * 4 + 0], l0);
                atomicAdd(&pool[bbid * 64 + tx * 4 + 1], l1);
                atomicAdd(&pool[bbid * 64 + tx * 4 + 2], l2);
                atomicAdd(&pool[bbid * 64 + tx * 4 + 3], l3);
            }
        }
    }

    if (do_pool) {
        __syncthreads();
        atomicAdd(&psum[t], pool[t]);
        if (t < 64) {
            const int gr = r0 + t;
            const int bv = (gr < N) ? bid[gr] : -1;
            #pragma unroll
            for (int b2 = 0; b2 < 4; ++b2) {
                unsigned long long mk = __ballot(bv == b2);
                if (t == 0) atomicAdd(&pcnts[b2], (float)__popcll(mk));
            }
        }
    }
}

// ---------------- K4: epilogue: v -> @hW -> *q -> @pW ----------------------
__global__ __launch_bounds__(256) void k_final(
    const float* __restrict__ ln0, const float* __restrict__ ln1,
    const float* __restrict__ ln2, const float* __restrict__ gates,
    const float* __restrict__ qbuf, const int* __restrict__ bid,
    const float* __restrict__ psum, const float* __restrict__ pcnts,
    const float* __restrict__ hW, const float* __restrict__ hb,
    const float* __restrict__ pW, const float* __restrict__ pb,
    float* __restrict__ out, int N)
{
    __shared__ float sV[64 * 68];
    __shared__ float sH[4096];
    __shared__ float sP[4096];
    __shared__ float spool[256];
    const int t = threadIdx.x, tx = t & 15, ty = t >> 4;
    const int r0 = blockIdx.x * 64;

    for (int e = t; e < 1024; e += 256) {
        ((float4*)sH)[e] = ((const float4*)hW)[e];
        ((float4*)sP)[e] = ((const float4*)pW)[e];
    }
    spool[t] = gelu_exact(psum[t] / pcnts[t >> 6]);
    __syncthreads();                       // spool ready for staging reads

    #pragma unroll
    for (int rr = 0; rr < 4; ++rr) {
        int r = ty + rr * 16;
        int gr = r0 + r; if (gr >= N) gr = N - 1;
        const float4 gt = *(const float4*)&gates[(size_t)gr * 4];
        const int bb = bid[gr];
        const float4 l0 = *(const float4*)&ln0[(size_t)gr * 64 + tx * 4];
        const float4 l1 = *(const float4*)&ln1[(size_t)gr * 64 + tx * 4];
        const float4 l2 = *(const float4*)&ln2[(size_t)gr * 64 + tx * 4];
        const float4 sp = *(const float4*)&spool[bb * 64 + tx * 4];
        sV[(tx * 4 + 0) * 68 + r] = l0.x * gt.x + l1.x * gt.y + l2.x * gt.z + sp.x * gt.w;
        sV[(tx * 4 + 1) * 68 + r] = l0.y * gt.x + l1.y * gt.y + l2.y * gt.z + sp.y * gt.w;
        sV[(tx * 4 + 2) * 68 + r] = l0.z * gt.x + l1.z * gt.y + l2.z * gt.z + sp.z * gt.w;
        sV[(tx * 4 + 3) * 68 + r] = l0.w * gt.x + l1.w * gt.y + l2.w * gt.z + sp.w * gt.w;
    }
    __syncthreads();

    const float4 bh = *(const float4*)&hb[tx * 4];
    float t1[4][4];
    #pragma unroll
    for (int m = 0; m < 4; ++m) {
        t1[m][0] = bh.x; t1[m][1] = bh.y; t1[m][2] = bh.z; t1[m][3] = bh.w;
    }
    #pragma unroll
    for (int k = 0; k < 64; ++k) {
        const float4 a = *(const float4*)&sV[k * 68 + ty * 4];
        const float4 w = *(const float4*)&sH[k * 64 + tx * 4];
        const float av[4] = {a.x, a.y, a.z, a.w};
        #pragma unroll
        for (int m = 0; m < 4; ++m) {
            t1[m][0] = fmaf(av[m], w.x, t1[m][0]);
            t1[m][1] = fmaf(av[m], w.y, t1[m][1]);
            t1[m][2] = fmaf(av[m], w.z, t1[m][2]);
            t1[m][3] = fmaf(av[m], w.w, t1[m][3]);
        }
    }
    float u[4][4];
    #pragma unroll
    for (int m = 0; m < 4; ++m) {
        int gr = r0 + ty * 4 + m; if (gr >= N) gr = N - 1;
        const float4 qv = *(const float4*)&qbuf[(size_t)gr * 64 + tx * 4];
        u[m][0] = qv.x * t1[m][0]; u[m][1] = qv.y * t1[m][1];
        u[m][2] = qv.z * t1[m][2]; u[m][3] = qv.w * t1[m][3];
    }
    __syncthreads();                       // all sV (v) reads + qbuf reads complete
    #pragma unroll
    for (int m = 0; m < 4; ++m) {
        #pragma unroll
        for (int i = 0; i < 4; ++i)
            sV[(tx * 4 + i) * 68 + ty * 4 + m] = u[m][i];
    }
    __syncthreads();

    const float4 bp = *(const float4*)&pb[tx * 4];
    float o[4][4];
    #pragma unroll
    for (int m = 0; m < 4; ++m) {
        o[m][0] = bp.x; o[m][1] = bp.y; o[m][2] = bp.z; o[m][3] = bp.w;
    }
    #pragma unroll
    for (int k = 0; k < 64; ++k) {
        const float4 a = *(const float4*)&sV[k * 68 + ty * 4];
        const float4 w = *(const float4*)&sP[k * 64 + tx * 4];
        const float av[4] = {a.x, a.y, a.z, a.w};
        #pragma unroll
        for (int m = 0; m < 4; ++m) {
            o[m][0] = fmaf(av[m], w.x, o[m][0]);
            o[m][1] = fmaf(av[m], w.y, o[m][1]);
            o[m][2] = fmaf(av[m], w.z, o[m][2]);
            o[m][3] = fmaf(av[m], w.w, o[m][3]);
        }
    }
    #pragma unroll
    for (int m = 0; m < 4; ++m) {
        const int gr = r0 + ty * 4 + m;
        if (gr < N) {
            float4 ov = {o[m][0], o[m][1], o[m][2], o[m][3]};
            *(float4*)&out[(size_t)gr * 64 + tx * 4] = ov;
        }
    }
}

// ---------------------------------------------------------------------------
extern "C" void kernel_launch(void* const* d_in, const int* in_sizes, int n_in,
                              void* d_out, int out_size, void* d_ws, size_t ws_size,
                              hipStream_t stream)
{
    const float* feat = (const float*)d_in[0];
    const float* fW   = (const float*)d_in[1];
    const float* fb   = (const float*)d_in[2];
    const float* hW   = (const float*)d_in[3];
    const float* hb   = (const float*)d_in[4];
    const float* pW   = (const float*)d_in[5];
    const float* pb   = (const float*)d_in[6];
    const int*   bid  = (const int*)d_in[7];
    const float* w[3]  = {(const float*)d_in[8],  (const float*)d_in[13], (const float*)d_in[18]};
    const float* bc[3] = {(const float*)d_in[9],  (const float*)d_in[14], (const float*)d_in[19]};
    const float* g[3]  = {(const float*)d_in[10], (const float*)d_in[15], (const float*)d_in[20]};
    const float* be[3] = {(const float*)d_in[11], (const float*)d_in[16], (const float*)d_in[21]};
    const int*  idx[3] = {(const int*)d_in[12],   (const int*)d_in[17],   (const int*)d_in[22]};

    const int N = in_sizes[0] / 64;

    // Workspace layout (floats). q lives in d_out; ln2 reuses ctx0's buffer.
    float* ws     = (float*)d_ws;
    float* sbuf   = ws;                          // N*64, zeroed once
    float* psum   = sbuf + (size_t)N * 64;       // 256, zeroed
    float* pcnts  = psum + 256;                  // 4, zeroed
    float* gates  = pcnts + 4;                   // N*4 (16B-aligned)
    float* ctx0   = gates + (size_t)N * 4;       // N*64 (becomes ln2)
    float* ln0    = ctx0 + (size_t)N * 64;       // N*64
    float* ln1    = ln0 + (size_t)N * 64;        // N*64
    float* ln2    = ctx0;                        // alias: ctx0 dead after level 0
    float* q      = (float*)d_out;               // alias: epilogue reads then writes

    hipMemsetAsync(sbuf, 0, ((size_t)N * 64 + 260) * sizeof(float), stream);

    const dim3 blk(256);
    const int NT = (N + 63) / 64;                // 64-row tiles

    k_fused_in<<<NT, blk, 0, stream>>>(feat, fW, fb, q, ctx0, gates, N);

    const int Ks[3] = {27, 125, 343};
    const int Cs[3] = {16, 8, 6};
    const float* cins[3] = {ctx0, ln0, ln1};
    float*       lns[3]  = {ln0, ln1, ln2};
    for (int l = 0; l < 3; ++l) {
        const int K = Ks[l], C = Cs[l];
        const int center = (K - 1) / 2;
        const int seg = (((N + C - 1) / C) + 3) & ~3;
        k_sparse<<<K * C, blk, 0, stream>>>(cins[l], idx[l], w[l], sbuf, N, center, C, seg);
        k_post  <<<NT,    blk, 0, stream>>>(cins[l], sbuf, w[l], bc[l], g[l], be[l], bid,
                                            lns[l], psum, pcnts, N, center,
                                            (l < 2) ? 1 : 0, (l == 2) ? 1 : 0);
    }

    k_final<<<NT, blk, 0, stream>>>(ln0, ln1, ln2, gates, q, bid, psum, pcnts,
                                    hW, hb, pW, pb, (float*)d_out, N);
}

// Round 11
// 300.137 us; speedup vs baseline: 2.1141x; 2.1141x over previous
//
#include <hip/hip_runtime.h>
#include <math.h>

// SparseFocalModulation — round 11: fix k_fused_in register-spill catastrophe
// (R10: VGPR=256, 600MB/dispatch scratch traffic). Two-pass q/ctx split +
// bounded unroll (8) on all dense GEMM k-loops.

#define PL 1024   // plist capacity (pairs) per sparse block; expected ~18

__device__ __forceinline__ float gelu_exact(float x) {
    return 0.5f * x * (1.0f + erff(x * 0.70710678118654752440f));
}

// ---------------- K1: xf = feat @ f_W + f_b ; split into q / ctx / gates ----
__global__ __launch_bounds__(256) void k_fused_in(
    const float* __restrict__ feat, const float* __restrict__ fW,
    const float* __restrict__ fb, float* __restrict__ q,
    float* __restrict__ ctx, float* __restrict__ gates, int N)
{
    __shared__ float sA[64 * 68];     // feat_T[k][r]
    __shared__ float sW[64 * 132];    // fW row-major (all 132 cols)
    const int t = threadIdx.x, tx = t & 15, ty = t >> 4;
    const int r0 = blockIdx.x * 64;

    for (int e = t; e < 2112; e += 256)            // 64 rows x 33 float4
        ((float4*)sW)[e] = ((const float4*)fW)[e];
    #pragma unroll
    for (int rr = 0; rr < 4; ++rr) {
        int r = ty + rr * 16;
        int gr = r0 + r; if (gr >= N) gr = N - 1;
        float4 v = *(const float4*)&feat[(size_t)gr * 64 + tx * 4];
        sA[(tx * 4 + 0) * 68 + r] = v.x;
        sA[(tx * 4 + 1) * 68 + r] = v.y;
        sA[(tx * 4 + 2) * 68 + r] = v.z;
        sA[(tx * 4 + 3) * 68 + r] = v.w;
    }
    __syncthreads();

    // ---- pass 1: q half (cols 0..63) ----
    {
        const float4 bq = *(const float4*)&fb[tx * 4];
        float acc[4][4];
        #pragma unroll
        for (int m = 0; m < 4; ++m) {
            acc[m][0] = bq.x; acc[m][1] = bq.y; acc[m][2] = bq.z; acc[m][3] = bq.w;
        }
        #pragma unroll 8
        for (int k = 0; k < 64; ++k) {
            const float4 a = *(const float4*)&sA[k * 68 + ty * 4];
            const float4 w = *(const float4*)&sW[k * 132 + tx * 4];
            const float av[4] = {a.x, a.y, a.z, a.w};
            #pragma unroll
            for (int m = 0; m < 4; ++m) {
                acc[m][0] = fmaf(av[m], w.x, acc[m][0]);
                acc[m][1] = fmaf(av[m], w.y, acc[m][1]);
                acc[m][2] = fmaf(av[m], w.z, acc[m][2]);
                acc[m][3] = fmaf(av[m], w.w, acc[m][3]);
            }
        }
        #pragma unroll
        for (int m = 0; m < 4; ++m) {
            const int gr = r0 + ty * 4 + m;
            if (gr < N) {
                float4 o = {acc[m][0], acc[m][1], acc[m][2], acc[m][3]};
                *(float4*)&q[(size_t)gr * 64 + tx * 4] = o;
            }
        }
    }

    // ---- pass 2: ctx half (cols 64..127) ----
    {
        const float4 bc = *(const float4*)&fb[64 + tx * 4];
        float acc[4][4];
        #pragma unroll
        for (int m = 0; m < 4; ++m) {
            acc[m][0] = bc.x; acc[m][1] = bc.y; acc[m][2] = bc.z; acc[m][3] = bc.w;
        }
        #pragma unroll 8
        for (int k = 0; k < 64; ++k) {
            const float4 a = *(const float4*)&sA[k * 68 + ty * 4];
            const float4 w = *(const float4*)&sW[k * 132 + 64 + tx * 4];
            const float av[4] = {a.x, a.y, a.z, a.w};
            #pragma unroll
            for (int m = 0; m < 4; ++m) {
                acc[m][0] = fmaf(av[m], w.x, acc[m][0]);
                acc[m][1] = fmaf(av[m], w.y, acc[m][1]);
                acc[m][2] = fmaf(av[m], w.z, acc[m][2]);
                acc[m][3] = fmaf(av[m], w.w, acc[m][3]);
            }
        }
        #pragma unroll
        for (int m = 0; m < 4; ++m) {
            const int gr = r0 + ty * 4 + m;
            if (gr < N) {
                float4 o = {acc[m][0], acc[m][1], acc[m][2], acc[m][3]};
                *(float4*)&ctx[(size_t)gr * 64 + tx * 4] = o;
            }
        }
    }

    // ---- gates: col j = tx&3, k-range split over tx>>2 (16 k each) ----
    {
        float accg[4] = {0.f, 0.f, 0.f, 0.f};
        const int j = tx & 3, ks0 = (tx >> 2) * 16;
        #pragma unroll
        for (int kk = 0; kk < 16; ++kk) {
            const int k = ks0 + kk;
            const float4 a = *(const float4*)&sA[k * 68 + ty * 4];
            const float gw = sW[k * 132 + 128 + j];
            accg[0] = fmaf(a.x, gw, accg[0]);
            accg[1] = fmaf(a.y, gw, accg[1]);
            accg[2] = fmaf(a.z, gw, accg[2]);
            accg[3] = fmaf(a.w, gw, accg[3]);
        }
        #pragma unroll
        for (int m = 0; m < 4; ++m) {
            accg[m] += __shfl_xor(accg[m], 4);
            accg[m] += __shfl_xor(accg[m], 8);
        }
        const float bg = fb[128 + j];
        #pragma unroll
        for (int m = 0; m < 4; ++m) {
            const int gr = r0 + ty * 4 + m;
            if (gr < N && tx < 4)
                gates[(size_t)gr * 4 + j] = accg[m] + bg;
        }
    }
}

// ---------------- K2: sparse non-center offsets -> atomicAdd into sbuf ------
__global__ __launch_bounds__(256) void k_sparse(
    const float* __restrict__ ctx, const int* __restrict__ idx,
    const float* __restrict__ W, float* __restrict__ sbuf,
    int N, int center, int nchunk, int seg)
{
    const int o = blockIdx.x / nchunk;
    if (o == center) return;
    const int chunk = blockIdx.x % nchunk;

    __shared__ int plist[2 * PL];
    __shared__ int pcnt;
    __shared__ float sW[4096];
    if (threadIdx.x == 0) pcnt = 0;
    __syncthreads();

    const int start = chunk * seg;
    const int end   = min(N, start + seg);
    const int* row  = idx + (size_t)o * N;
    if (((N | start) & 3) == 0) {
        const int4* row4 = reinterpret_cast<const int4*>(row + start);
        const int n4 = (end - start) >> 2;
        for (int t = threadIdx.x; t < n4; t += 256) {
            int4 v = row4[t];
            int base = start + t * 4;
            if (v.x >= 0) { int p = atomicAdd(&pcnt, 1); if (p < PL) { plist[2*p] = base;     plist[2*p+1] = v.x; } }
            if (v.y >= 0) { int p = atomicAdd(&pcnt, 1); if (p < PL) { plist[2*p] = base + 1; plist[2*p+1] = v.y; } }
            if (v.z >= 0) { int p = atomicAdd(&pcnt, 1); if (p < PL) { plist[2*p] = base + 2; plist[2*p+1] = v.z; } }
            if (v.w >= 0) { int p = atomicAdd(&pcnt, 1); if (p < PL) { plist[2*p] = base + 3; plist[2*p+1] = v.w; } }
        }
    } else {
        for (int t = start + threadIdx.x; t < end; t += 256) {
            int j = row[t];
            if (j >= 0) { int p = atomicAdd(&pcnt, 1); if (p < PL) { plist[2*p] = t; plist[2*p+1] = j; } }
        }
    }
    __syncthreads();

    const int cnt = min(pcnt, PL);
    if (cnt == 0) return;
    for (int t = threadIdx.x; t < 4096; t += 256) sW[t] = W[(size_t)o * 4096 + t];
    __syncthreads();

    const int lane = threadIdx.x & 63;
    const int lwid = threadIdx.x >> 6;
    for (int p = lwid; p < cnt; p += 4) {
        int i = plist[2 * p];
        int j = plist[2 * p + 1];
        float cv  = ctx[(size_t)j * 64 + lane];
        float acc = 0.0f;
        #pragma unroll
        for (int c = 0; c < 64; ++c)
            acc = fmaf(__shfl(cv, c), sW[c * 64 + lane], acc);
        atomicAdd(&sbuf[(size_t)i * 64 + lane], acc);
    }
}

// ------- K3: y = center-matvec + sbuf + b; ln = LN(gelu(y)); opt. pooling ---
__global__ __launch_bounds__(256) void k_post(
    const float* __restrict__ cin, float* __restrict__ sbuf,
    const float* __restrict__ W, const float* __restrict__ b,
    const float* __restrict__ g, const float* __restrict__ be,
    const int* __restrict__ bid, float* __restrict__ lnout,
    float* __restrict__ psum, float* __restrict__ pcnts,
    int N, int center, int zero_sbuf, int do_pool)
{
    __shared__ float sA[64 * 68];
    __shared__ float sW[64 * 64];
    __shared__ float pool[256];
    const int t = threadIdx.x, tx = t & 15, ty = t >> 4;
    const int r0 = blockIdx.x * 64;

    const float* Wc = W + (size_t)center * 4096;
    for (int e = t; e < 1024; e += 256)
        ((float4*)sW)[e] = ((const float4*)Wc)[e];
    if (do_pool) pool[t] = 0.f;
    #pragma unroll
    for (int rr = 0; rr < 4; ++rr) {
        int r = ty + rr * 16;
        int gr = r0 + r; if (gr >= N) gr = N - 1;
        float4 v = *(const float4*)&cin[(size_t)gr * 64 + tx * 4];
        sA[(tx * 4 + 0) * 68 + r] = v.x;
        sA[(tx * 4 + 1) * 68 + r] = v.y;
        sA[(tx * 4 + 2) * 68 + r] = v.z;
        sA[(tx * 4 + 3) * 68 + r] = v.w;
    }
    __syncthreads();

    const float4 bb4 = *(const float4*)&b[tx * 4];
    float acc[4][4];
    #pragma unroll
    for (int m = 0; m < 4; ++m) {
        const int gr = r0 + ty * 4 + m;
        if (gr < N) {
            float4 s4 = *(const float4*)&sbuf[(size_t)gr * 64 + tx * 4];
            acc[m][0] = bb4.x + s4.x; acc[m][1] = bb4.y + s4.y;
            acc[m][2] = bb4.z + s4.z; acc[m][3] = bb4.w + s4.w;
            if (zero_sbuf) {
                float4 z = {0.f, 0.f, 0.f, 0.f};
                *(float4*)&sbuf[(size_t)gr * 64 + tx * 4] = z;
            }
        } else {
            acc[m][0] = acc[m][1] = acc[m][2] = acc[m][3] = 0.f;
        }
    }
    #pragma unroll 8
    for (int k = 0; k < 64; ++k) {
        const float4 a = *(const float4*)&sA[k * 68 + ty * 4];
        const float4 w = *(const float4*)&sW[k * 64 + tx * 4];
        const float av[4] = {a.x, a.y, a.z, a.w};
        #pragma unroll
        for (int m = 0; m < 4; ++m) {
            acc[m][0] = fmaf(av[m], w.x, acc[m][0]);
            acc[m][1] = fmaf(av[m], w.y, acc[m][1]);
            acc[m][2] = fmaf(av[m], w.z, acc[m][2]);
            acc[m][3] = fmaf(av[m], w.w, acc[m][3]);
        }
    }

    const float4 g4  = *(const float4*)&g[tx * 4];
    const float4 be4 = *(const float4*)&be[tx * 4];
    #pragma unroll
    for (int m = 0; m < 4; ++m) {
        const int gr = r0 + ty * 4 + m;
        float v0 = gelu_exact(acc[m][0]);
        float v1 = gelu_exact(acc[m][1]);
        float v2 = gelu_exact(acc[m][2]);
        float v3 = gelu_exact(acc[m][3]);
        float s = v0 + v1 + v2 + v3;
        s += __shfl_xor(s, 1); s += __shfl_xor(s, 2);
        s += __shfl_xor(s, 4); s += __shfl_xor(s, 8);
        const float mean = s * 0.015625f;
        const float d0 = v0 - mean, d1 = v1 - mean, d2 = v2 - mean, d3 = v3 - mean;
        float vs = d0*d0 + d1*d1 + d2*d2 + d3*d3;
        vs += __shfl_xor(vs, 1); vs += __shfl_xor(vs, 2);
        vs += __shfl_xor(vs, 4); vs += __shfl_xor(vs, 8);
        const float rstd = rsqrtf(vs * 0.015625f + 1e-5f);
        const float l0 = d0 * rstd * g4.x + be4.x;
        const float l1 = d1 * rstd * g4.y + be4.y;
        const float l2 = d2 * rstd * g4.z + be4.z;
        const float l3 = d3 * rstd * g4.w + be4.w;
        if (gr < N) {
            float4 o = {l0, l1, l2, l3};
            *(float4*)&lnout[(size_t)gr * 64 + tx * 4] = o;
            if (do_pool) {
                const int bbid = bid[gr];
                atomicAdd(&pool[bbid * 64 + tx * 4 + 0], l0);
                atomicAdd(&pool[bbid * 64 + tx * 4 + 1], l1);
                atomicAdd(&pool[bbid * 64 + tx * 4 + 2], l2);
                atomicAdd(&pool[bbid * 64 + tx * 4 + 3], l3);
            }
        }
    }

    if (do_pool) {
        __syncthreads();
        atomicAdd(&psum[t], pool[t]);
        if (t < 64) {
            const int gr = r0 + t;
            const int bv = (gr < N) ? bid[gr] : -1;
            #pragma unroll
            for (int b2 = 0; b2 < 4; ++b2) {
                unsigned long long mk = __ballot(bv == b2);
                if (t == 0) atomicAdd(&pcnts[b2], (float)__popcll(mk));
            }
        }
    }
}

// ---------------- K4: epilogue: v -> @hW -> *q -> @pW ----------------------
__global__ __launch_bounds__(256) void k_final(
    const float* __restrict__ ln0, const float* __restrict__ ln1,
    const float* __restrict__ ln2, const float* __restrict__ gates,
    const float* __restrict__ qbuf, const int* __restrict__ bid,
    const float* __restrict__ psum, const float* __restrict__ pcnts,
    const float* __restrict__ hW, const float* __restrict__ hb,
    const float* __restrict__ pW, const float* __restrict__ pb,
    float* __restrict__ out, int N)
{
    __shared__ float sV[64 * 68];
    __shared__ float sH[4096];
    __shared__ float sP[4096];
    __shared__ float spool[256];
    const int t = threadIdx.x, tx = t & 15, ty = t >> 4;
    const int r0 = blockIdx.x * 64;

    for (int e = t; e < 1024; e += 256) {
        ((float4*)sH)[e] = ((const float4*)hW)[e];
        ((float4*)sP)[e] = ((const float4*)pW)[e];
    }
    spool[t] = gelu_exact(psum[t] / pcnts[t >> 6]);
    __syncthreads();                       // spool ready for staging reads

    #pragma unroll
    for (int rr = 0; rr < 4; ++rr) {
        int r = ty + rr * 16;
        int gr = r0 + r; if (gr >= N) gr = N - 1;
        const float4 gt = *(const float4*)&gates[(size_t)gr * 4];
        const int bb = bid[gr];
        const float4 l0 = *(const float4*)&ln0[(size_t)gr * 64 + tx * 4];
        const float4 l1 = *(const float4*)&ln1[(size_t)gr * 64 + tx * 4];
        const float4 l2 = *(const float4*)&ln2[(size_t)gr * 64 + tx * 4];
        const float4 sp = *(const float4*)&spool[bb * 64 + tx * 4];
        sV[(tx * 4 + 0) * 68 + r] = l0.x * gt.x + l1.x * gt.y + l2.x * gt.z + sp.x * gt.w;
        sV[(tx * 4 + 1) * 68 + r] = l0.y * gt.x + l1.y * gt.y + l2.y * gt.z + sp.y * gt.w;
        sV[(tx * 4 + 2) * 68 + r] = l0.z * gt.x + l1.z * gt.y + l2.z * gt.z + sp.z * gt.w;
        sV[(tx * 4 + 3) * 68 + r] = l0.w * gt.x + l1.w * gt.y + l2.w * gt.z + sp.w * gt.w;
    }
    __syncthreads();

    const float4 bh = *(const float4*)&hb[tx * 4];
    float t1[4][4];
    #pragma unroll
    for (int m = 0; m < 4; ++m) {
        t1[m][0] = bh.x; t1[m][1] = bh.y; t1[m][2] = bh.z; t1[m][3] = bh.w;
    }
    #pragma unroll 8
    for (int k = 0; k < 64; ++k) {
        const float4 a = *(const float4*)&sV[k * 68 + ty * 4];
        const float4 w = *(const float4*)&sH[k * 64 + tx * 4];
        const float av[4] = {a.x, a.y, a.z, a.w};
        #pragma unroll
        for (int m = 0; m < 4; ++m) {
            t1[m][0] = fmaf(av[m], w.x, t1[m][0]);
            t1[m][1] = fmaf(av[m], w.y, t1[m][1]);
            t1[m][2] = fmaf(av[m], w.z, t1[m][2]);
            t1[m][3] = fmaf(av[m], w.w, t1[m][3]);
        }
    }
    float u[4][4];
    #pragma unroll
    for (int m = 0; m < 4; ++m) {
        int gr = r0 + ty * 4 + m; if (gr >= N) gr = N - 1;
        const float4 qv = *(const float4*)&qbuf[(size_t)gr * 64 + tx * 4];
        u[m][0] = qv.x * t1[m][0]; u[m][1] = qv.y * t1[m][1];
        u[m][2] = qv.z * t1[m][2]; u[m][3] = qv.w * t1[m][3];
    }
    __syncthreads();                       // all sV (v) reads + qbuf reads complete
    #pragma unroll
    for (int m = 0; m < 4; ++m) {
        #pragma unroll
        for (int i = 0; i < 4; ++i)
            sV[(tx * 4 + i) * 68 + ty * 4 + m] = u[m][i];
    }
    __syncthreads();

    const float4 bp = *(const float4*)&pb[tx * 4];
    float o[4][4];
    #pragma unroll
    for (int m = 0; m < 4; ++m) {
        o[m][0] = bp.x; o[m][1] = bp.y; o[m][2] = bp.z; o[m][3] = bp.w;
    }
    #pragma unroll 8
    for (int k = 0; k < 64; ++k) {
        const float4 a = *(const float4*)&sV[k * 68 + ty * 4];
        const float4 w = *(const float4*)&sP[k * 64 + tx * 4];
        const float av[4] = {a.x, a.y, a.z, a.w};
        #pragma unroll
        for (int m = 0; m < 4; ++m) {
            o[m][0] = fmaf(av[m], w.x, o[m][0]);
            o[m][1] = fmaf(av[m], w.y, o[m][1]);
            o[m][2] = fmaf(av[m], w.z, o[m][2]);
            o[m][3] = fmaf(av[m], w.w, o[m][3]);
        }
    }
    #pragma unroll
    for (int m = 0; m < 4; ++m) {
        const int gr = r0 + ty * 4 + m;
        if (gr < N) {
            float4 ov = {o[m][0], o[m][1], o[m][2], o[m][3]};
            *(float4*)&out[(size_t)gr * 64 + tx * 4] = ov;
        }
    }
}

// ---------------------------------------------------------------------------
extern "C" void kernel_launch(void* const* d_in, const int* in_sizes, int n_in,
                              void* d_out, int out_size, void* d_ws, size_t ws_size,
                              hipStream_t stream)
{
    const float* feat = (const float*)d_in[0];
    const float* fW   = (const float*)d_in[1];
    const float* fb   = (const float*)d_in[2];
    const float* hW   = (const float*)d_in[3];
    const float* hb   = (const float*)d_in[4];
    const float* pW   = (const float*)d_in[5];
    const float* pb   = (const float*)d_in[6];
    const int*   bid  = (const int*)d_in[7];
    const float* w[3]  = {(const float*)d_in[8],  (const float*)d_in[13], (const float*)d_in[18]};
    const float* bc[3] = {(const float*)d_in[9],  (const float*)d_in[14], (const float*)d_in[19]};
    const float* g[3]  = {(const float*)d_in[10], (const float*)d_in[15], (const float*)d_in[20]};
    const float* be[3] = {(const float*)d_in[11], (const float*)d_in[16], (const float*)d_in[21]};
    const int*  idx[3] = {(const int*)d_in[12],   (const int*)d_in[17],   (const int*)d_in[22]};

    const int N = in_sizes[0] / 64;

    // Workspace layout (floats). q lives in d_out; ln2 reuses ctx0's buffer.
    float* ws     = (float*)d_ws;
    float* sbuf   = ws;                          // N*64, zeroed once
    float* psum   = sbuf + (size_t)N * 64;       // 256, zeroed
    float* pcnts  = psum + 256;                  // 4, zeroed
    float* gates  = pcnts + 4;                   // N*4 (16B-aligned)
    float* ctx0   = gates + (size_t)N * 4;       // N*64 (becomes ln2)
    float* ln0    = ctx0 + (size_t)N * 64;       // N*64
    float* ln1    = ln0 + (size_t)N * 64;        // N*64
    float* ln2    = ctx0;                        // alias: ctx0 dead after level 0
    float* q      = (float*)d_out;               // alias: epilogue reads then writes

    hipMemsetAsync(sbuf, 0, ((size_t)N * 64 + 260) * sizeof(float), stream);

    const dim3 blk(256);
    const int NT = (N + 63) / 64;                // 64-row tiles

    k_fused_in<<<NT, blk, 0, stream>>>(feat, fW, fb, q, ctx0, gates, N);

    const int Ks[3] = {27, 125, 343};
    const int Cs[3] = {16, 8, 6};
    const float* cins[3] = {ctx0, ln0, ln1};
    float*       lns[3]  = {ln0, ln1, ln2};
    for (int l = 0; l < 3; ++l) {
        const int K = Ks[l], C = Cs[l];
        const int center = (K - 1) / 2;
        const int seg = (((N + C - 1) / C) + 3) & ~3;
        k_sparse<<<K * C, blk, 0, stream>>>(cins[l], idx[l], w[l], sbuf, N, center, C, seg);
        k_post  <<<NT,    blk, 0, stream>>>(cins[l], sbuf, w[l], bc[l], g[l], be[l], bid,
                                            lns[l], psum, pcnts, N, center,
                                            (l < 2) ? 1 : 0, (l == 2) ? 1 : 0);
    }

    k_final<<<NT, blk, 0, stream>>>(ln0, ln1, ln2, gates, q, bid, psum, pcnts,
                                    hW, hb, pW, pb, (float*)d_out, N);
}